// Round 10
// baseline (218.644 us; speedup 1.0000x reference)
//
#include <hip/hip_runtime.h>

#define NNODES 4096
#define DIM 512
#define QKVD 1536
#define MAXE 96    // bucket capacity per dst row
#define VSTAGE 44  // V rows staged in LDS (P(deg>=44) ~ 2%; tail reads global)

typedef __bf16 bf16_t;
typedef bf16_t bf16x8 __attribute__((ext_vector_type(8)));
typedef bf16_t bf16x4 __attribute__((ext_vector_type(4)));
typedef float f32x4 __attribute__((ext_vector_type(4)));
typedef unsigned int uint;

#define GLOAD_LDS16(gp, lp)                                                             \
  __builtin_amdgcn_global_load_lds((const __attribute__((address_space(1))) void*)(gp), \
                                   (__attribute__((address_space(3))) void*)(lp), 16, 0, 0)

// ---------------- fused casts f32 -> bf16 (+ deg & counter zero) ----------------
__global__ __launch_bounds__(256) void cast_all_k(const float* __restrict__ x,
                                                  const float* __restrict__ wqkv,
                                                  const float* __restrict__ wo,
                                                  const float* __restrict__ w1,
                                                  bf16_t* __restrict__ xb,
                                                  bf16_t* __restrict__ wqkvb,
                                                  bf16_t* __restrict__ wob,
                                                  bf16_t* __restrict__ w1b,
                                                  uint* __restrict__ deg,
                                                  uint* __restrict__ cnt) {
  int i = blockIdx.x * 256 + threadIdx.x;
  if (blockIdx.x < 16) deg[i] = 0u;  // 16*256 = 4096 rows
  if (blockIdx.x == 16 && threadIdx.x < 64) cnt[threadIdx.x] = 0u;
  const float* src;
  bf16_t* dst;
  int off;
  if (i < 524288) { src = x; dst = xb; off = i; }
  else if (i < 720896) { src = wqkv; dst = wqkvb; off = i - 524288; }
  else if (i < 786432) { src = wo; dst = wob; off = i - 720896; }
  else { src = w1; dst = w1b; off = i - 786432; }
  float4 v = ((const float4*)src)[off];
  dst[4 * off + 0] = (bf16_t)v.x;
  dst[4 * off + 1] = (bf16_t)v.y;
  dst[4 * off + 2] = (bf16_t)v.z;
  dst[4 * off + 3] = (bf16_t)v.w;
}

// ---------------- QKV GEMM (128x128, bf16 out) + bucket CSR fill, one dispatch ----------------
// blocks [0,384): GEMM tiles; blocks [384, 384+ceil(E/256)): edge fill
__global__ __launch_bounds__(256) void qkv_fill_k(const bf16_t* __restrict__ A,
                                                  const bf16_t* __restrict__ B,
                                                  const float* __restrict__ bias,
                                                  bf16_t* __restrict__ Cout,
                                                  const int* __restrict__ ei,
                                                  uint* __restrict__ deg,
                                                  int* __restrict__ colv,
                                                  uint* __restrict__ eidv, int E) {
  __shared__ bf16_t As[128][40];
  __shared__ bf16_t Bs[128][40];
  const int bid = blockIdx.x;
  const int t = threadIdx.x;

  if (bid >= 384) {  // ---- edge fill path ----
    int e = (bid - 384) * 256 + t;
    if (e < E) {
      int src = ei[e] & (NNODES - 1);
      int dst = ei[E + e] & (NNODES - 1);
      uint pos = atomicAdd(&deg[dst], 1u);
      if (pos < MAXE) {
        colv[dst * MAXE + pos] = src;
        eidv[dst * MAXE + pos] = (uint)e + 1u;  // 0 reserved for diagonal self-entry
      }
    }
    return;
  }

  // ---- GEMM path: tile 128x128, Nt=1536, K=512 ----
  const int lane = t & 63, w = t >> 6;
  const int wr = (w >> 1) * 64, wc = (w & 1) * 64;
  const int m0 = (bid / 12) * 128, n0 = (bid % 12) * 128;
  f32x4 acc[4][4] = {};
  const int r_ld = t >> 2;
  const int c_ld = (t & 3) * 8;

  for (int k0 = 0; k0 < 512; k0 += 32) {
#pragma unroll
    for (int seg = 0; seg < 2; ++seg) {
      int row = r_ld + seg * 64;
      *(int4*)&As[row][c_ld] = *(const int4*)(A + (long)(m0 + row) * 512 + k0 + c_ld);
      *(int4*)&Bs[row][c_ld] = *(const int4*)(B + (long)(n0 + row) * 512 + k0 + c_ld);
    }
    __syncthreads();
    bf16x8 af[4], bfr[4];
    const int kg = (lane >> 4) * 8;
#pragma unroll
    for (int i = 0; i < 4; ++i) {
      af[i] = *(const bf16x8*)&As[wr + i * 16 + (lane & 15)][kg];
      bfr[i] = *(const bf16x8*)&Bs[wc + i * 16 + (lane & 15)][kg];
    }
#pragma unroll
    for (int i = 0; i < 4; ++i)
#pragma unroll
      for (int j = 0; j < 4; ++j)
        acc[i][j] = __builtin_amdgcn_mfma_f32_16x16x32_bf16(af[i], bfr[j], acc[i][j], 0, 0, 0);
    __syncthreads();
  }

  const int cr = (lane >> 4) * 4;
  const int cc = lane & 15;
#pragma unroll
  for (int i = 0; i < 4; ++i) {
#pragma unroll
    for (int j = 0; j < 4; ++j) {
      int n = n0 + wc + j * 16 + cc;
      float bv = bias[n];
#pragma unroll
      for (int r = 0; r < 4; ++r) {
        int m = m0 + wr + i * 16 + cr + r;
        Cout[(long)m * QKVD + n] = (bf16_t)(acc[i][j][r] + bv);
      }
    }
  }
}

// ---------------- fused sparse attention v3 ----------------
// 512 thr (8 waves) per dst row. V async-staged to LDS early (hidden under K-dots);
// K dots from global (register, clamped 4-way); dedupe parallel over all threads;
// vld mask applied at softmax read.
__global__ __launch_bounds__(512) void attn_v3_k(const bf16_t* __restrict__ qkv,
                                                 const float* __restrict__ ew,
                                                 const uint* __restrict__ deg,
                                                 const int* __restrict__ colv,
                                                 const uint* __restrict__ eidv,
                                                 bf16_t* __restrict__ outb) {
  __shared__ __align__(16) bf16_t vstage[VSTAGE][DIM];  // 45,056 B (reused as vacc)
  __shared__ float scs[8][MAXE + 1];
  __shared__ int srcs[MAXE + 1];
  __shared__ uint eids[MAXE + 1];
  __shared__ int vld[MAXE + 1];
  __shared__ float invs_s[8];

  const int i = blockIdx.x;
  const int t = threadIdx.x;
  const int lane = t & 63, w = t >> 6;  // w in 0..7

  // Q row early (independent of CSR)
  const bf16x8 qv = *(const bf16x8*)(qkv + (long)i * QKVD + lane * 8);

  uint dg = deg[i];
  int L = (dg < (uint)MAXE) ? (int)dg : MAXE;
  int n = L + 1;
  int ns = (n < VSTAGE) ? n : VSTAGE;

  if (t < L) {
    srcs[t] = colv[i * MAXE + t];
    eids[t] = eidv[i * MAXE + t];
  }
  if (t == L) { srcs[L] = i; eids[L] = 0u; }
  if (t <= L) vld[t] = 1;
  __syncthreads();

  // ---- issue V staging (async, zero VGPR); consumed 2 barriers later ----
  for (int e = w; e < ns; e += 8)
    GLOAD_LDS16(qkv + (long)srcs[e] * QKVD + 2 * DIM + lane * 8, &vstage[e][0]);

  // ---- K dots from global, clamped 4-way; raw scores (mask deferred) ----
  for (int e = w; e < n; e += 32) {
    int ec[4], val[4];
#pragma unroll
    for (int u = 0; u < 4; ++u) {
      int ee = e + 8 * u;
      val[u] = ee < n;
      ec[u] = val[u] ? ee : e;
    }
    bf16x8 kr[4];
#pragma unroll
    for (int u = 0; u < 4; ++u)
      kr[u] = *(const bf16x8*)(qkv + (long)srcs[ec[u]] * QKVD + DIM + lane * 8);
    float d0[4] = {0.f, 0.f, 0.f, 0.f};
#pragma unroll
    for (int j = 0; j < 8; ++j) {
      float q = (float)qv[j];
#pragma unroll
      for (int u = 0; u < 4; ++u) d0[u] += q * (float)kr[u][j];
    }
#pragma unroll
    for (int o = 1; o < 8; o <<= 1) {
#pragma unroll
      for (int u = 0; u < 4; ++u) d0[u] += __shfl_xor(d0[u], o);
    }
    if ((lane & 7) == 0) {
      int hh = lane >> 3;
#pragma unroll
      for (int u = 0; u < 4; ++u) {
        if (val[u]) {
          uint id = eids[ec[u]];
          float b = (id == 0u) ? 0.f : ew[id - 1u];
          scs[hh][ec[u]] = d0[u] * 0.125f + b;
        }
      }
    }
  }

  // ---- dedupe in parallel across all 512 threads (last edge-id wins per src) ----
  {
    int tot = n * n;
    for (int idx = t; idx < tot; idx += 512) {
      int a = idx / n, b = idx - a * n;
      if (srcs[b] == srcs[a] && eids[b] > eids[a]) vld[a] = 0;
    }
  }
  __syncthreads();  // scores + vld ready; V staging drained

  // ---- softmax: wave w handles head w; vld mask applied here ----
  {
    float m = -1e30f;
    for (int e = lane; e < n; e += 64) {
      float sv = vld[e] ? scs[w][e] : -1e30f;
      m = fmaxf(m, sv);
    }
#pragma unroll
    for (int o = 32; o > 0; o >>= 1) m = fmaxf(m, __shfl_xor(m, o));
    float ps = 0.f;
    for (int e = lane; e < n; e += 64) {
      float sv = vld[e] ? scs[w][e] : -1e30f;
      float ev = __expf(sv - m);
      scs[w][e] = ev;  // invalid entries -> exactly 0
      ps += ev;
    }
#pragma unroll
    for (int o = 32; o > 0; o >>= 1) ps += __shfl_xor(ps, o);
    if (lane == 0) invs_s[w] = 1.f / ps;
  }
  __syncthreads();

  // ---- PV: staged entries from LDS, rare tail from global ----
  const int hl = lane >> 3;
  float a8[8] = {0.f, 0.f, 0.f, 0.f, 0.f, 0.f, 0.f, 0.f};
  for (int e = w; e < n; e += 8) {
    bf16x8 vr;
    if (e < ns)
      vr = *(const bf16x8*)&vstage[e][lane * 8];
    else
      vr = *(const bf16x8*)(qkv + (long)srcs[e] * QKVD + 2 * DIM + lane * 8);
    float p = scs[hl][e];
#pragma unroll
    for (int j = 0; j < 8; ++j) a8[j] += p * (float)vr[j];
  }
  __syncthreads();  // vstage reads done -> reuse as vacc

  float* vacc = (float*)&vstage[0][0];  // 8 x 512 f32 = 16 KB
#pragma unroll
  for (int j = 0; j < 8; ++j) vacc[w * DIM + lane * 8 + j] = a8[j];
  __syncthreads();
  {
    float s = 0.f;
#pragma unroll
    for (int ww = 0; ww < 8; ++ww) s += vacc[ww * DIM + t];
    outb[(long)i * DIM + t] = (bf16_t)(s * invs_s[t >> 6]);
  }
}

// ---------------- GEMM 128x64 (f32 out) + tile-counter-fused residual+LayerNorm ----------------
// C = A @ B^T + bias (f32, Nt=512, K=512). Last block of each 128-row slice computes
// outf = LN(res + C) * g + beta (and optional bf16 copy).
template <bool HB>
__global__ __launch_bounds__(256) void gemm_ln_k(const bf16_t* __restrict__ A,
                                                 const bf16_t* __restrict__ B,
                                                 const float* __restrict__ bias,
                                                 float* __restrict__ Cf,
                                                 const float* __restrict__ res,
                                                 const float* __restrict__ g,
                                                 const float* __restrict__ beta,
                                                 float* __restrict__ outf,
                                                 bf16_t* __restrict__ outbb,
                                                 uint* __restrict__ cnt) {
  __shared__ bf16_t As[128][40];
  __shared__ bf16_t Bs[64][40];
  __shared__ uint lastFlag;
  const int t = threadIdx.x;
  const int lane = t & 63, w = t >> 6;
  const int wr = (w >> 1) * 64, wc = (w & 1) * 32;
  const int m0 = blockIdx.y * 128, n0 = blockIdx.x * 64;
  f32x4 acc[4][2] = {};
  const int r_ld = t >> 2;
  const int c_ld = (t & 3) * 8;

  for (int k0 = 0; k0 < 512; k0 += 32) {
    *(int4*)&As[r_ld][c_ld] = *(const int4*)(A + (long)(m0 + r_ld) * 512 + k0 + c_ld);
    *(int4*)&As[r_ld + 64][c_ld] = *(const int4*)(A + (long)(m0 + r_ld + 64) * 512 + k0 + c_ld);
    *(int4*)&Bs[r_ld][c_ld] = *(const int4*)(B + (long)(n0 + r_ld) * 512 + k0 + c_ld);
    __syncthreads();
    bf16x8 af[4], bfr[2];
    const int kg = (lane >> 4) * 8;
#pragma unroll
    for (int i = 0; i < 4; ++i)
      af[i] = *(const bf16x8*)&As[wr + i * 16 + (lane & 15)][kg];
#pragma unroll
    for (int j = 0; j < 2; ++j)
      bfr[j] = *(const bf16x8*)&Bs[wc + j * 16 + (lane & 15)][kg];
#pragma unroll
    for (int i = 0; i < 4; ++i)
#pragma unroll
      for (int j = 0; j < 2; ++j)
        acc[i][j] = __builtin_amdgcn_mfma_f32_16x16x32_bf16(af[i], bfr[j], acc[i][j], 0, 0, 0);
    __syncthreads();
  }

  const int cr = (lane >> 4) * 4;
  const int cc = lane & 15;
#pragma unroll
  for (int i = 0; i < 4; ++i) {
#pragma unroll
    for (int j = 0; j < 2; ++j) {
      int n = n0 + wc + j * 16 + cc;
      float bv = bias[n];
#pragma unroll
      for (int r = 0; r < 4; ++r) {
        int m = m0 + wr + i * 16 + cr + r;
        Cf[(long)m * 512 + n] = acc[i][j][r] + bv;
      }
    }
  }

  // ---- release: make this block's tile visible, then count ----
  __threadfence();
  __syncthreads();
  if (t == 0) lastFlag = (atomicAdd(&cnt[blockIdx.y], 1u) == 7u) ? 1u : 0u;
  __syncthreads();
  if (!lastFlag) return;

  // ---- finisher: LN over rows [m0, m0+128) ----
  __threadfence();  // acquire
  // hoist g/beta (8 elems per lane)
  float gv[8], bv8[8];
#pragma unroll
  for (int j = 0; j < 2; ++j)
#pragma unroll
    for (int c = 0; c < 4; ++c) {
      int d = j * 256 + lane * 4 + c;
      gv[j * 4 + c] = g[d];
      bv8[j * 4 + c] = beta[d];
    }
  for (int rb = 0; rb < 32; rb += 4) {
    float4 xa[4][2], wa[4][2];
#pragma unroll
    for (int u = 0; u < 4; ++u) {
      int row = m0 + w * 32 + rb + u;
      const float4* pr = (const float4*)(res + (long)row * 512);
      const float4* pc = (const float4*)(Cf + (long)row * 512);
      xa[u][0] = pr[lane];
      xa[u][1] = pr[lane + 64];
      wa[u][0] = pc[lane];
      wa[u][1] = pc[lane + 64];
    }
#pragma unroll
    for (int u = 0; u < 4; ++u) {
      int row = m0 + w * 32 + rb + u;
      float vv[8];
      float s = 0.f;
#pragma unroll
      for (int j = 0; j < 2; ++j) {
        vv[j * 4 + 0] = xa[u][j].x + wa[u][j].x;
        vv[j * 4 + 1] = xa[u][j].y + wa[u][j].y;
        vv[j * 4 + 2] = xa[u][j].z + wa[u][j].z;
        vv[j * 4 + 3] = xa[u][j].w + wa[u][j].w;
#pragma unroll
        for (int c = 0; c < 4; ++c) s += vv[j * 4 + c];
      }
#pragma unroll
      for (int o = 32; o > 0; o >>= 1) s += __shfl_xor(s, o);
      float mu = s * (1.f / 512.f);
      float q = 0.f;
#pragma unroll
      for (int c = 0; c < 8; ++c) {
        float dd = vv[c] - mu;
        q += dd * dd;
      }
#pragma unroll
      for (int o = 32; o > 0; o >>= 1) q += __shfl_xor(q, o);
      float inv = rsqrtf(q * (1.f / 512.f) + 1e-5f);
#pragma unroll
      for (int j = 0; j < 2; ++j) {
        float4 y4;
        bf16x4 b4;
#pragma unroll
        for (int c = 0; c < 4; ++c) {
          float y = (vv[j * 4 + c] - mu) * inv * gv[j * 4 + c] + bv8[j * 4 + c];
          ((float*)&y4)[c] = y;
          b4[c] = (bf16_t)y;
        }
        *(float4*)(outf + (long)row * 512 + j * 256 + lane * 4) = y4;
        if (HB) *(bf16x4*)(outbb + (long)row * 512 + j * 256 + lane * 4) = b4;
      }
    }
  }
}

// ---------------- launch ----------------
extern "C" void kernel_launch(void* const* d_in, const int* in_sizes, int n_in,
                              void* d_out, int out_size, void* d_ws, size_t ws_size,
                              hipStream_t stream) {
  const float* x = (const float*)d_in[0];
  const int* ei = (const int*)d_in[1];
  const float* ew = (const float*)d_in[2];
  const float* Wqkv = (const float*)d_in[3];
  const float* bqkv = (const float*)d_in[4];
  const float* Wo = (const float*)d_in[5];
  const float* bo = (const float*)d_in[6];
  const float* W1 = (const float*)d_in[7];
  const float* b1 = (const float*)d_in[8];
  const float* g1 = (const float*)d_in[9];
  const float* be1 = (const float*)d_in[10];
  const float* g2 = (const float*)d_in[11];
  const float* be2 = (const float*)d_in[12];
  float* out = (float*)d_out;
  const int E = in_sizes[1] / 2;

  char* ws = (char*)d_ws;
  bf16_t* qkvb = (bf16_t*)(ws + 0);           // 12,582,912 B
  bf16_t* xb = (bf16_t*)(ws + 12582912);      // 4,194,304
  bf16_t* Wqkvb = (bf16_t*)(ws + 16777216);   // 1,572,864
  bf16_t* Wob = (bf16_t*)(ws + 18350080);     // 524,288
  bf16_t* W1b = (bf16_t*)(ws + 18874368);     // 524,288
  bf16_t* outb = (bf16_t*)(ws + 19398656);    // 4,194,304
  float* h = (float*)(ws + 23592960);         // 8,388,608
  bf16_t* hb = (bf16_t*)(ws + 31981568);      // 4,194,304
  float* f = (float*)(ws + 36175872);         // 8,388,608 (end 44,564,480)
  uint* cnt = (uint*)(ws + 44564480);         // 64 uints (cnt1 = [0:32), cnt2 = [32:64))
  // CSR buffers alias the h region (h written only after attention done)
  uint* deg = (uint*)(ws + 23592960);         // 16,384
  int* colv = (int*)(ws + 23609344);          // 1,572,864
  uint* eidv = (uint*)(ws + 25182208);        // 1,572,864 (end 26,755,072 < h end)
  float* attn_out = (float*)(ws + 0);         // alias over dead qkvb

  // 1: casts + zero deg/counters
  cast_all_k<<<3328, 256, 0, stream>>>(x, Wqkv, Wo, W1, xb, Wqkvb, Wob, W1b, deg, cnt);

  // 2: QKV GEMM + edge fill (merged)
  qkv_fill_k<<<384 + (E + 255) / 256, 256, 0, stream>>>(
      xb, Wqkvb, bqkv, qkvb, ei, deg, colv, eidv, E);

  // 3: fused sparse attention
  attn_v3_k<<<NNODES, 512, 0, stream>>>(qkvb, ew, deg, colv, eidv, outb);

  // 4: Wo projection + residual(x) + LN1 -> h (f32) + hb (bf16)
  gemm_ln_k<true><<<dim3(8, 32), 256, 0, stream>>>(
      outb, Wob, bo, attn_out, x, g1, be1, h, hb, cnt);

  // 5: FFN + residual(h) + LN2 -> out
  gemm_ln_k<false><<<dim3(8, 32), 256, 0, stream>>>(
      hb, W1b, b1, f, h, g2, be2, out, nullptr, cnt + 32);
}

// Round 11
// 107.111 us; speedup vs baseline: 2.0413x; 2.0413x over previous
//
#include <hip/hip_runtime.h>

#define NNODES 4096
#define DIM 512
#define QKVD 1536
#define MAXE 96  // bucket capacity per dst row (Poisson(32): P(deg>96) ~ 1e-18)

typedef __bf16 bf16_t;
typedef bf16_t bf16x8 __attribute__((ext_vector_type(8)));
typedef bf16_t bf16x2 __attribute__((ext_vector_type(2)));
typedef float f32x4 __attribute__((ext_vector_type(4)));
typedef unsigned int uint;

// ---------------- fused casts f32 -> bf16 (+ deg zero) ----------------
__global__ __launch_bounds__(256) void cast_all_k(const float* __restrict__ x,
                                                  const float* __restrict__ wqkv,
                                                  const float* __restrict__ wo,
                                                  const float* __restrict__ w1,
                                                  bf16_t* __restrict__ xb,
                                                  bf16_t* __restrict__ wqkvb,
                                                  bf16_t* __restrict__ wob,
                                                  bf16_t* __restrict__ w1b,
                                                  uint* __restrict__ deg) {
  int i = blockIdx.x * 256 + threadIdx.x;
  if (blockIdx.x < 16) deg[i] = 0u;  // 16*256 = 4096 rows
  const float* src;
  bf16_t* dst;
  int off;
  if (i < 524288) { src = x; dst = xb; off = i; }
  else if (i < 720896) { src = wqkv; dst = wqkvb; off = i - 524288; }
  else if (i < 786432) { src = wo; dst = wob; off = i - 720896; }
  else { src = w1; dst = w1b; off = i - 786432; }
  float4 v = ((const float4*)src)[off];
  dst[4 * off + 0] = (bf16_t)v.x;
  dst[4 * off + 1] = (bf16_t)v.y;
  dst[4 * off + 2] = (bf16_t)v.z;
  dst[4 * off + 3] = (bf16_t)v.w;
}

// ---------------- QKV GEMM (128x128, bf16 out) + bucket CSR fill, one dispatch ----------------
// blocks [0,384): GEMM tiles; blocks [384, 384+ceil(E/256)): edge fill
__global__ __launch_bounds__(256) void qkv_fill_k(const bf16_t* __restrict__ A,
                                                  const bf16_t* __restrict__ B,
                                                  const float* __restrict__ bias,
                                                  bf16_t* __restrict__ Cout,
                                                  const int* __restrict__ ei,
                                                  uint* __restrict__ deg,
                                                  int* __restrict__ colv,
                                                  uint* __restrict__ eidv, int E) {
  __shared__ bf16_t As[128][40];
  __shared__ bf16_t Bs[128][40];
  const int bid = blockIdx.x;
  const int t = threadIdx.x;

  if (bid >= 384) {  // ---- edge fill path ----
    int e = (bid - 384) * 256 + t;
    if (e < E) {
      int src = ei[e] & (NNODES - 1);
      int dst = ei[E + e] & (NNODES - 1);
      uint pos = atomicAdd(&deg[dst], 1u);
      if (pos < MAXE) {
        colv[dst * MAXE + pos] = src;
        eidv[dst * MAXE + pos] = (uint)e + 1u;  // 0 reserved for diagonal self-entry
      }
    }
    return;
  }

  // ---- GEMM path: tile 128x128, Nt=1536, K=512 ----
  const int lane = t & 63, w = t >> 6;
  const int wr = (w >> 1) * 64, wc = (w & 1) * 64;
  const int m0 = (bid / 12) * 128, n0 = (bid % 12) * 128;
  f32x4 acc[4][4] = {};
  const int r_ld = t >> 2;
  const int c_ld = (t & 3) * 8;

  for (int k0 = 0; k0 < 512; k0 += 32) {
#pragma unroll
    for (int seg = 0; seg < 2; ++seg) {
      int row = r_ld + seg * 64;
      *(int4*)&As[row][c_ld] = *(const int4*)(A + (long)(m0 + row) * 512 + k0 + c_ld);
      *(int4*)&Bs[row][c_ld] = *(const int4*)(B + (long)(n0 + row) * 512 + k0 + c_ld);
    }
    __syncthreads();
    bf16x8 af[4], bfr[4];
    const int kg = (lane >> 4) * 8;
#pragma unroll
    for (int i = 0; i < 4; ++i) {
      af[i] = *(const bf16x8*)&As[wr + i * 16 + (lane & 15)][kg];
      bfr[i] = *(const bf16x8*)&Bs[wc + i * 16 + (lane & 15)][kg];
    }
#pragma unroll
    for (int i = 0; i < 4; ++i)
#pragma unroll
      for (int j = 0; j < 4; ++j)
        acc[i][j] = __builtin_amdgcn_mfma_f32_16x16x32_bf16(af[i], bfr[j], acc[i][j], 0, 0, 0);
    __syncthreads();
  }

  const int cr = (lane >> 4) * 4;
  const int cc = lane & 15;
#pragma unroll
  for (int i = 0; i < 4; ++i) {
#pragma unroll
    for (int j = 0; j < 4; ++j) {
      int n = n0 + wc + j * 16 + cc;
      float bv = bias[n];
#pragma unroll
      for (int r = 0; r < 4; ++r) {
        int m = m0 + wr + i * 16 + cr + r;
        Cout[(long)m * QKVD + n] = (bf16_t)(acc[i][j][r] + bv);
      }
    }
  }
}

// ---------------- bf16 MFMA GEMM: C = A @ B^T + bias, tile 128x64 (Wo/FFN) ----------------
template <bool OUT_BF16>
__global__ __launch_bounds__(256) void gemm_bt(const bf16_t* __restrict__ A,
                                               const bf16_t* __restrict__ B,
                                               const float* __restrict__ bias,
                                               void* __restrict__ Cout,
                                               int M, int Nt, int K) {
  __shared__ bf16_t As[128][40];
  __shared__ bf16_t Bs[64][40];
  const int t = threadIdx.x;
  const int lane = t & 63, w = t >> 6;
  const int wr = (w >> 1) * 64, wc = (w & 1) * 32;
  const int m0 = blockIdx.y * 128, n0 = blockIdx.x * 64;
  f32x4 acc[4][2] = {};
  const int r_ld = t >> 2;
  const int c_ld = (t & 3) * 8;

  for (int k0 = 0; k0 < K; k0 += 32) {
    *(int4*)&As[r_ld][c_ld] = *(const int4*)(A + (long)(m0 + r_ld) * K + k0 + c_ld);
    *(int4*)&As[r_ld + 64][c_ld] = *(const int4*)(A + (long)(m0 + r_ld + 64) * K + k0 + c_ld);
    *(int4*)&Bs[r_ld][c_ld] = *(const int4*)(B + (long)(n0 + r_ld) * K + k0 + c_ld);
    __syncthreads();
    bf16x8 af[4], bfr[2];
    const int kg = (lane >> 4) * 8;
#pragma unroll
    for (int i = 0; i < 4; ++i)
      af[i] = *(const bf16x8*)&As[wr + i * 16 + (lane & 15)][kg];
#pragma unroll
    for (int j = 0; j < 2; ++j)
      bfr[j] = *(const bf16x8*)&Bs[wc + j * 16 + (lane & 15)][kg];
#pragma unroll
    for (int i = 0; i < 4; ++i)
#pragma unroll
      for (int j = 0; j < 2; ++j)
        acc[i][j] = __builtin_amdgcn_mfma_f32_16x16x32_bf16(af[i], bfr[j], acc[i][j], 0, 0, 0);
    __syncthreads();
  }

  const int cr = (lane >> 4) * 4;
  const int cc = lane & 15;
#pragma unroll
  for (int i = 0; i < 4; ++i) {
#pragma unroll
    for (int j = 0; j < 2; ++j) {
      int n = n0 + wc + j * 16 + cc;
      float bv = bias[n];
#pragma unroll
      for (int r = 0; r < 4; ++r) {
        int m = m0 + wr + i * 16 + cr + r;
        float vv = acc[i][j][r] + bv;
        if (OUT_BF16)
          ((bf16_t*)Cout)[(long)m * Nt + n] = (bf16_t)vv;
        else
          ((float*)Cout)[(long)m * Nt + n] = vv;
      }
    }
  }
}

// ---------------- fused sparse attention (round-4 measured-best) ----------------
// one block (256 thr) per dst row; score/PV wave-parallel over entries, 2-way unrolled
__global__ __launch_bounds__(256) void attn_fused_k(const bf16_t* __restrict__ qkv,
                                                    const float* __restrict__ ew,
                                                    const uint* __restrict__ deg,
                                                    const int* __restrict__ colv,
                                                    const uint* __restrict__ eidv,
                                                    bf16_t* __restrict__ outb) {
  __shared__ float scs[8][MAXE + 1];
  __shared__ int srcs[MAXE + 1];
  __shared__ uint eids[MAXE + 1];
  __shared__ int vld[MAXE + 1];
  __shared__ float invs_s[8];
  __shared__ float vacc[4][DIM];

  const int i = blockIdx.x;
  const int t = threadIdx.x;
  const int lane = t & 63, w = t >> 6;

  uint dg = deg[i];
  int L = (dg < (uint)MAXE) ? (int)dg : MAXE;
  int n = L + 1;

  if (t < L) {
    srcs[t] = colv[i * MAXE + t];
    eids[t] = eidv[i * MAXE + t];
  }
  if (t == L) { srcs[L] = i; eids[L] = 0u; }
  __syncthreads();

  // deterministic dedupe (last edge-id wins per src)
  if (t < n) {
    int sj = srcs[t];
    uint my = eids[t];
    int ok = 1;
    for (int j = 0; j < n; ++j)
      ok &= !((srcs[j] == sj) & (eids[j] > my));
    vld[t] = ok;
  }
  __syncthreads();

  // scores: wave per entry (stride 4), 2-way unrolled; lane = 16B chunk of K row
  const bf16x8 qv = *(const bf16x8*)(qkv + (long)i * QKVD + lane * 8);
  {
    int e = w;
    for (; e + 4 < n; e += 8) {
      int sa = srcs[e], sb = srcs[e + 4];
      const bf16x8 ka = *(const bf16x8*)(qkv + (long)sa * QKVD + DIM + lane * 8);
      const bf16x8 kb = *(const bf16x8*)(qkv + (long)sb * QKVD + DIM + lane * 8);
      float s0 = 0.f, s1 = 0.f;
#pragma unroll
      for (int j = 0; j < 8; ++j) {
        s0 += (float)qv[j] * (float)ka[j];
        s1 += (float)qv[j] * (float)kb[j];
      }
      s0 += __shfl_xor(s0, 1); s1 += __shfl_xor(s1, 1);
      s0 += __shfl_xor(s0, 2); s1 += __shfl_xor(s1, 2);
      s0 += __shfl_xor(s0, 4); s1 += __shfl_xor(s1, 4);
      if ((lane & 7) == 0) {
        int h = lane >> 3;
        float b0 = (eids[e] == 0u) ? 0.f : ew[eids[e] - 1u];
        float b1 = (eids[e + 4] == 0u) ? 0.f : ew[eids[e + 4] - 1u];
        scs[h][e] = vld[e] ? (s0 * 0.125f + b0) : -1e30f;
        scs[h][e + 4] = vld[e + 4] ? (s1 * 0.125f + b1) : -1e30f;
      }
    }
    if (e < n) {
      int sa = srcs[e];
      const bf16x8 ka = *(const bf16x8*)(qkv + (long)sa * QKVD + DIM + lane * 8);
      float s0 = 0.f;
#pragma unroll
      for (int j = 0; j < 8; ++j) s0 += (float)qv[j] * (float)ka[j];
      s0 += __shfl_xor(s0, 1);
      s0 += __shfl_xor(s0, 2);
      s0 += __shfl_xor(s0, 4);
      if ((lane & 7) == 0) {
        int h = lane >> 3;
        float b0 = (eids[e] == 0u) ? 0.f : ew[eids[e] - 1u];
        scs[h][e] = vld[e] ? (s0 * 0.125f + b0) : -1e30f;
      }
    }
  }
  __syncthreads();

  // softmax: wave w handles heads 2w, 2w+1
#pragma unroll
  for (int hh = 0; hh < 2; ++hh) {
    int h = w * 2 + hh;
    float m = -1e30f;
    for (int e = lane; e < n; e += 64) m = fmaxf(m, scs[h][e]);
#pragma unroll
    for (int o = 32; o > 0; o >>= 1) m = fmaxf(m, __shfl_xor(m, o));
    float ps = 0.f;
    for (int e = lane; e < n; e += 64) {
      float ev = __expf(scs[h][e] - m);
      scs[h][e] = ev;  // invalid entries become exactly 0
      ps += ev;
    }
#pragma unroll
    for (int o = 32; o > 0; o >>= 1) ps += __shfl_xor(ps, o);
    if (lane == 0) invs_s[h] = 1.f / ps;
  }
  __syncthreads();

  // PV: wave-parallel over entries (stride 4), 2-way unrolled; lane = 8 dims
  const int hl = lane >> 3;
  float a8[8] = {0.f, 0.f, 0.f, 0.f, 0.f, 0.f, 0.f, 0.f};
  {
    int e = w;
    for (; e + 4 < n; e += 8) {
      const bf16x8 v0 = *(const bf16x8*)(qkv + (long)srcs[e] * QKVD + 2 * DIM + lane * 8);
      const bf16x8 v1 = *(const bf16x8*)(qkv + (long)srcs[e + 4] * QKVD + 2 * DIM + lane * 8);
      float p0 = scs[hl][e], p1 = scs[hl][e + 4];
#pragma unroll
      for (int j = 0; j < 8; ++j) a8[j] += p0 * (float)v0[j] + p1 * (float)v1[j];
    }
    if (e < n) {
      const bf16x8 v0 = *(const bf16x8*)(qkv + (long)srcs[e] * QKVD + 2 * DIM + lane * 8);
      float p0 = scs[hl][e];
#pragma unroll
      for (int j = 0; j < 8; ++j) a8[j] += p0 * (float)v0[j];
    }
  }
#pragma unroll
  for (int j = 0; j < 8; ++j) vacc[w][lane * 8 + j] = a8[j];
  __syncthreads();

  // final cross-wave reduce: thread t -> dims 2t, 2t+1
  {
    const int d0 = 2 * t;
    const int h = t >> 5;
    const float inv = invs_s[h];
    float s0 = vacc[0][d0] + vacc[1][d0] + vacc[2][d0] + vacc[3][d0];
    float s1 = vacc[0][d0 + 1] + vacc[1][d0 + 1] + vacc[2][d0 + 1] + vacc[3][d0 + 1];
    bf16x2 o2;
    o2[0] = (bf16_t)(s0 * inv);
    o2[1] = (bf16_t)(s1 * inv);
    *(bf16x2*)(outb + (long)i * DIM + d0) = o2;
  }
}

// ---------------- LayerNorm(a+b) ----------------
__global__ __launch_bounds__(64) void ln_k(const float* __restrict__ a,
                                           const float* __restrict__ b,
                                           const float* __restrict__ g,
                                           const float* __restrict__ beta,
                                           float* __restrict__ of,
                                           bf16_t* __restrict__ ob) {
  const int row = blockIdx.x;
  const int l = threadIdx.x;
  const float* pa = a + (long)row * DIM;
  const float* pb = b + (long)row * DIM;
  float v[8];
  float s = 0.f;
#pragma unroll
  for (int j = 0; j < 8; ++j) {
    int d = l + j * 64;
    v[j] = pa[d] + pb[d];
    s += v[j];
  }
#pragma unroll
  for (int o = 32; o > 0; o >>= 1) s += __shfl_xor(s, o);
  float mu = s * (1.f / 512.f);
  float q = 0.f;
#pragma unroll
  for (int j = 0; j < 8; ++j) {
    float dd = v[j] - mu;
    q += dd * dd;
  }
#pragma unroll
  for (int o = 32; o > 0; o >>= 1) q += __shfl_xor(q, o);
  float inv = rsqrtf(q * (1.f / 512.f) + 1e-5f);
#pragma unroll
  for (int j = 0; j < 8; ++j) {
    int d = l + j * 64;
    float y = (v[j] - mu) * inv * g[d] + beta[d];
    of[(long)row * DIM + d] = y;
    if (ob) ob[(long)row * DIM + d] = (bf16_t)y;
  }
}

// ---------------- launch ----------------
extern "C" void kernel_launch(void* const* d_in, const int* in_sizes, int n_in,
                              void* d_out, int out_size, void* d_ws, size_t ws_size,
                              hipStream_t stream) {
  const float* x = (const float*)d_in[0];
  const int* ei = (const int*)d_in[1];
  const float* ew = (const float*)d_in[2];
  const float* Wqkv = (const float*)d_in[3];
  const float* bqkv = (const float*)d_in[4];
  const float* Wo = (const float*)d_in[5];
  const float* bo = (const float*)d_in[6];
  const float* W1 = (const float*)d_in[7];
  const float* b1 = (const float*)d_in[8];
  const float* g1 = (const float*)d_in[9];
  const float* be1 = (const float*)d_in[10];
  const float* g2 = (const float*)d_in[11];
  const float* be2 = (const float*)d_in[12];
  float* out = (float*)d_out;
  const int E = in_sizes[1] / 2;

  char* ws = (char*)d_ws;
  bf16_t* qkvb = (bf16_t*)(ws + 0);           // 12,582,912 B
  bf16_t* xb = (bf16_t*)(ws + 12582912);      // 4,194,304
  bf16_t* Wqkvb = (bf16_t*)(ws + 16777216);   // 1,572,864
  bf16_t* Wob = (bf16_t*)(ws + 18350080);     // 524,288
  bf16_t* W1b = (bf16_t*)(ws + 18874368);     // 524,288
  bf16_t* outb = (bf16_t*)(ws + 19398656);    // 4,194,304
  float* h = (float*)(ws + 23592960);         // 8,388,608
  bf16_t* hb = (bf16_t*)(ws + 31981568);      // 4,194,304
  float* f = (float*)(ws + 36175872);         // 8,388,608 (end 44,564,480)
  // CSR buffers alias the h region (h is written only after attention is done)
  uint* deg = (uint*)(ws + 23592960);         // 16,384
  int* colv = (int*)(ws + 23609344);          // 1,572,864
  uint* eidv = (uint*)(ws + 25182208);        // 1,572,864 (end 26,755,072 < h end)
  float* attn_out = (float*)(ws + 0);         // alias over dead qkvb

  // 1: casts + deg zero
  cast_all_k<<<3328, 256, 0, stream>>>(x, Wqkv, Wo, W1, xb, Wqkvb, Wob, W1b, deg);

  // 2: QKV GEMM (128x128) + edge fill, merged
  qkv_fill_k<<<384 + (E + 255) / 256, 256, 0, stream>>>(
      xb, Wqkvb, bqkv, qkvb, ei, deg, colv, eidv, E);

  // 3: fused sparse attention (round-4 structure, measured best)
  attn_fused_k<<<NNODES, 256, 0, stream>>>(qkvb, ew, deg, colv, eidv, outb);

  // 4: output projection (f32 out, aliases qkvb space)
  gemm_bt<false><<<dim3(DIM / 64, NNODES / 128), 256, 0, stream>>>(
      outb, Wob, bo, (void*)attn_out, NNODES, DIM, DIM);

  // 5: LN1: h = LN(x + attn_out), also bf16 copy for FFN GEMM
  ln_k<<<NNODES, 64, 0, stream>>>(x, attn_out, g1, be1, h, hb);

  // 6: FFN: f = hb @ W1^T + b1
  gemm_bt<false><<<dim3(DIM / 64, NNODES / 128), 256, 0, stream>>>(
      hb, W1b, b1, (void*)f, NNODES, DIM, DIM);

  // 7: LN2 -> out
  ln_k<<<NNODES, 64, 0, stream>>>(h, f, g2, be2, out, nullptr);
}